// Round 3
// baseline (95.433 us; speedup 1.0000x reference)
//
#include <hip/hip_runtime.h>
#include <math.h>

#define NNODE 32768   // B*N
#define EE 128
constexpr float SCALE = 0.08838834764831845f; // 1/sqrt(128)

typedef unsigned short u16;
typedef __bf16 bf16x8 __attribute__((ext_vector_type(8)));
typedef float f32x4 __attribute__((ext_vector_type(4)));

__device__ __forceinline__ u16 f2bf(float f) {
    unsigned u = __float_as_uint(f);
    u += 0x7fff + ((u >> 16) & 1);       // RNE
    return (u16)(u >> 16);
}
__device__ __forceinline__ float bf2f(u16 h) {
    return __uint_as_float(((unsigned)h) << 16);
}

// async global->LDS, 16B per lane; LDS dest must be wave-uniform base
__device__ __forceinline__ void gl_lds16(const void* g, void* l) {
    __builtin_amdgcn_global_load_lds(
        (const __attribute__((address_space(1))) unsigned int*)(uintptr_t)g,
        (__attribute__((address_space(3))) unsigned int*)(unsigned int)(uintptr_t)l,
        16, 0, 0);
}

// ---------------- kernel 0: X f32 -> bf16 ------------------------------
__global__ __launch_bounds__(256) void xconv(const float* __restrict__ X,
                                             u16* __restrict__ Xb)
{
    int t = blockIdx.x * 256 + threadIdx.x;   // one thread = 8 elems
    float4 a = *(const float4*)&X[(size_t)t * 8];
    float4 b = *(const float4*)&X[(size_t)t * 8 + 4];
    u16 o[8] = { f2bf(a.x), f2bf(a.y), f2bf(a.z), f2bf(a.w),
                 f2bf(b.x), f2bf(b.y), f2bf(b.z), f2bf(b.w) };
    *(uint4*)&Xb[(size_t)t * 8] = *(const uint4*)o;
}

// ---------------- kernel 1: fold weights -------------------------------
// McatbT[col][e]  (bf16, [768][128])  col = dir*384 + which*128 + f
// bcat[col] f32
// PcatbT[f][e2]   (bf16, [128][256])  e2 = dir*128 + e
// bh[f] f32
__global__ __launch_bounds__(256) void fuse_weights(
    const float* __restrict__ Wq_in, const float* __restrict__ Wk_in,
    const float* __restrict__ Wv_in, const float* __restrict__ ipw_in,
    const float* __restrict__ ipb_in, const float* __restrict__ ow_in,
    const float* __restrict__ ob_in,
    const float* __restrict__ Wq_out, const float* __restrict__ Wk_out,
    const float* __restrict__ Wv_out, const float* __restrict__ ipw_out,
    const float* __restrict__ ipb_out, const float* __restrict__ ow_out,
    const float* __restrict__ ob_out,
    const float* __restrict__ lin_w, const float* __restrict__ lin_b,
    u16* __restrict__ McatbT, float* __restrict__ bcat,
    u16* __restrict__ PcatbT, float* __restrict__ bh)
{
    int t = blockIdx.x * 256 + threadIdx.x;
    if (t < 98304) {
        int col = t % 768, e = t / 768;
        int dir = col / 384, rem = col % 384;
        int which = rem / 128, f = rem % 128;
        const float* W = (dir == 0)
            ? (which == 0 ? Wq_in : which == 1 ? Wk_in : Wv_in)
            : (which == 0 ? Wq_out : which == 1 ? Wk_out : Wv_out);
        const float* ipw = (dir == 0) ? ipw_in : ipw_out;
        const float* wrow = ipw + (which * EE + f) * EE;
        const float* Wrow = W + e * EE;
        float s = 0.f;
        for (int c = 0; c < EE; ++c) s += Wrow[c] * wrow[c];
        McatbT[(size_t)col * 128 + e] = f2bf(s);
    } else if (t < 98304 + 768) {
        int col = t - 98304;
        int dir = col / 384, rem = col % 384;
        int which = rem / 128, f = rem % 128;
        const float* ipb = (dir == 0) ? ipb_in : ipb_out;
        bcat[col] = ipb[which * EE + f];
    } else if (t < 98304 + 768 + 32768) {
        int u = t - (98304 + 768);
        int e2 = u / 128, f = u % 128;
        int dir = e2 / 128, e = e2 % 128;
        const float* ow = (dir == 0) ? ow_in : ow_out;
        float s = 0.f;
        for (int c = 0; c < EE; ++c)
            s += lin_w[f * 256 + dir * 128 + c] * ow[c * EE + e];
        PcatbT[(size_t)f * 256 + e2] = f2bf(s);
    } else if (t < 98304 + 768 + 32768 + 128) {
        int f = t - (98304 + 768 + 32768);
        float s = lin_b[f];
        for (int c = 0; c < EE; ++c)
            s += ob_in[c] * lin_w[f * 256 + c] + ob_out[c] * lin_w[f * 256 + 128 + c];
        bh[f] = s;
    }
}

// ---------------- kernel 2: QKV GEMM (K=128, A-frags held in regs) -----
// C[32768][768] = A[32768][128] * BT[768][128]^T + bias; NT col-tiles/block
template<int NT>
__global__ __launch_bounds__(256) void gemm_qkv(
    const u16* __restrict__ A,
    const u16* __restrict__ BT,
    const float* __restrict__ bias,
    u16* __restrict__ C)
{
    __shared__ __align__(16) u16 As[128 * 128];
    __shared__ __align__(16) u16 Bs[128 * 128];
    const int tid  = threadIdx.x;
    const int lane = tid & 63;
    const int wid  = tid >> 6;
    const int bm  = blockIdx.x * 128;
    const int bn0 = blockIdx.y * (NT * 128);
    const int wr = wid >> 1, wc = wid & 1;
    const int l15 = lane & 15, l4 = lane >> 4;

    // stage A once (128x128, pre-swizzled source -> linear LDS)
    #pragma unroll
    for (int i = 0; i < 8; ++i) {
        int c = i * 256 + tid;
        int r = c >> 4, cb = c & 15;
        gl_lds16(&A[(size_t)(bm + r) * 128 + 8 * (cb ^ (r & 7))],
                 &As[(size_t)(c - lane) * 8]);
    }
    __syncthreads();
    bf16x8 a[4][4];
    #pragma unroll
    for (int ks = 0; ks < 4; ++ks)
        #pragma unroll
        for (int mr = 0; mr < 4; ++mr) {
            int r = wr * 64 + mr * 16 + l15;
            int kb = ks * 4 + l4;
            a[ks][mr] = *(const bf16x8*)((const char*)As + r * 256 + ((kb ^ (r & 7)) << 4));
        }

    #pragma unroll
    for (int nt = 0; nt < NT; ++nt) {
        int bn = bn0 + nt * 128;
        __syncthreads();                 // prior Bs consumers done
        #pragma unroll
        for (int i = 0; i < 8; ++i) {
            int c = i * 256 + tid;
            int r = c >> 4, cb = c & 15;
            gl_lds16(&BT[(size_t)(bn + r) * 128 + 8 * (cb ^ (r & 7))],
                     &Bs[(size_t)(c - lane) * 8]);
        }
        __syncthreads();

        f32x4 acc[4][4] = {};
        #pragma unroll
        for (int ks = 0; ks < 4; ++ks) {
            bf16x8 bfr[4];
            #pragma unroll
            for (int nc = 0; nc < 4; ++nc) {
                int r = wc * 64 + nc * 16 + l15;
                int kb = ks * 4 + l4;
                bfr[nc] = *(const bf16x8*)((const char*)Bs + r * 256 + ((kb ^ (r & 7)) << 4));
            }
            #pragma unroll
            for (int mr = 0; mr < 4; ++mr)
                #pragma unroll
                for (int nc = 0; nc < 4; ++nc)
                    acc[mr][nc] = __builtin_amdgcn_mfma_f32_16x16x32_bf16(
                        a[ks][mr], bfr[nc], acc[mr][nc], 0, 0, 0);
        }
        #pragma unroll
        for (int nc = 0; nc < 4; ++nc) {
            int col = bn + wc * 64 + nc * 16 + l15;
            float bv = bias[col];
            #pragma unroll
            for (int mr = 0; mr < 4; ++mr)
                #pragma unroll
                for (int j = 0; j < 4; ++j) {
                    int row = bm + wr * 64 + mr * 16 + l4 * 4 + j;
                    C[(size_t)row * 768 + col] = f2bf(acc[mr][nc][j] + bv);
                }
        }
    }
}

// ---------------- kernel 4: CTX GEMM + ELU (K=256) ---------------------
template<int KTOT, bool ELU_F32>
__global__ __launch_bounds__(256) void gemm_mfma(
    const u16* __restrict__ A,
    const u16* __restrict__ BT,
    const float* __restrict__ bias,
    void* __restrict__ Cout, int ldc)
{
    __shared__ __align__(16) u16 As[128 * 128];
    __shared__ __align__(16) u16 Bs[128 * 128];
    const int tid  = threadIdx.x;
    const int lane = tid & 63;
    const int wid  = tid >> 6;
    const int bm = blockIdx.x * 128;
    const int bn = blockIdx.y * 128;
    const int wr = wid >> 1, wc = wid & 1;
    const int l15 = lane & 15, l4 = lane >> 4;

    f32x4 acc[4][4] = {};

    for (int k0 = 0; k0 < KTOT; k0 += 128) {
        #pragma unroll
        for (int i = 0; i < 8; ++i) {
            int c = i * 256 + tid;
            int r = c >> 4, cb = c & 15;
            int col = k0 + 8 * (cb ^ (r & 7));
            gl_lds16(&A[(size_t)(bm + r) * KTOT + col], &As[(size_t)(c - lane) * 8]);
            gl_lds16(&BT[(size_t)(bn + r) * KTOT + col], &Bs[(size_t)(c - lane) * 8]);
        }
        __syncthreads();
        #pragma unroll
        for (int ks = 0; ks < 4; ++ks) {
            bf16x8 a[4], b[4];
            #pragma unroll
            for (int mr = 0; mr < 4; ++mr) {
                int r = wr * 64 + mr * 16 + l15;
                int kb = ks * 4 + l4;
                a[mr] = *(const bf16x8*)((const char*)As + r * 256 + ((kb ^ (r & 7)) << 4));
            }
            #pragma unroll
            for (int nc = 0; nc < 4; ++nc) {
                int r = wc * 64 + nc * 16 + l15;
                int kb = ks * 4 + l4;
                b[nc] = *(const bf16x8*)((const char*)Bs + r * 256 + ((kb ^ (r & 7)) << 4));
            }
            #pragma unroll
            for (int mr = 0; mr < 4; ++mr)
                #pragma unroll
                for (int nc = 0; nc < 4; ++nc)
                    acc[mr][nc] = __builtin_amdgcn_mfma_f32_16x16x32_bf16(
                        a[mr], b[nc], acc[mr][nc], 0, 0, 0);
        }
        __syncthreads();
    }

    #pragma unroll
    for (int nc = 0; nc < 4; ++nc) {
        int col = bn + wc * 64 + nc * 16 + l15;
        float bv = bias[col];
        #pragma unroll
        for (int mr = 0; mr < 4; ++mr) {
            #pragma unroll
            for (int j = 0; j < 4; ++j) {
                int row = bm + wr * 64 + mr * 16 + l4 * 4 + j;
                float v = acc[mr][nc][j] + bv;
                if (ELU_F32) {
                    v = v > 0.f ? v : (__expf(v) - 1.f);
                    ((float*)Cout)[(size_t)row * ldc + col] = v;
                } else {
                    ((u16*)Cout)[(size_t)row * ldc + col] = f2bf(v);
                }
            }
        }
    }
}

// ---------------- kernel 3: attention, XCD-partitioned + mask-skip -----
// blk&7 selects (dir, batch) pair -> with round-robin block->XCD dispatch,
// each XCD gathers only from its own 4MB (batch,dir) K/V pool (L2-sized).
__global__ __launch_bounds__(256) void attn_kernel(
    const u16* __restrict__ QKV,
    const int* __restrict__ in_idx, const int* __restrict__ out_idx,
    const int* __restrict__ in_mask, const int* __restrict__ out_mask,
    u16* __restrict__ CTX)
{
    int blk  = blockIdx.x;                 // 16384
    int dir  = blk & 1;
    int b    = (blk >> 1) & 3;
    int nl   = ((blk >> 3) << 2) + (threadIdx.x >> 6);   // 0..8191
    int node = (b << 13) + nl;
    int lane = threadIdx.x & 63;
    const int* idx = dir == 0 ? in_idx : out_idx;
    const int* msk = dir == 0 ? in_mask : out_mask;
    const int qoff = dir * 384;

    // broadcast loads of the 8 neighbor ids + masks (wave-uniform values)
    const int4 i0 = *(const int4*)&idx[(size_t)node * 8];
    const int4 i1 = *(const int4*)&idx[(size_t)node * 8 + 4];
    const int4 m0 = *(const int4*)&msk[(size_t)node * 8];
    const int4 m1 = *(const int4*)&msk[(size_t)node * 8 + 4];
    const int ii[8] = { i0.x, i0.y, i0.z, i0.w, i1.x, i1.y, i1.z, i1.w };
    const int mm[8] = { m0.x, m0.y, m0.z, m0.w, m1.x, m1.y, m1.z, m1.w };

    const u16* qrow = QKV + (size_t)node * 768 + qoff;
    ushort2 qu = *(const ushort2*)&qrow[lane * 2];
    float qx = bf2f(qu.x), qy = bf2f(qu.y);

    float sc[9], vx[9], vy[9];
    {
        const u16* krow = qrow + 128;
        ushort2 ku = *(const ushort2*)&krow[lane * 2];
        ushort2 vu = *(const ushort2*)&krow[128 + lane * 2];
        sc[0] = qx * bf2f(ku.x) + qy * bf2f(ku.y);
        vx[0] = bf2f(vu.x); vy[0] = bf2f(vu.y);
    }
    #pragma unroll
    for (int s = 1; s < 9; ++s) {
        if (mm[s - 1]) {   // wave-uniform: whole wave skips invalid slots
            const u16* krow = QKV + (size_t)((b << 13) + ii[s - 1]) * 768 + qoff + 128;
            ushort2 ku = *(const ushort2*)&krow[lane * 2];
            ushort2 vu = *(const ushort2*)&krow[128 + lane * 2];
            sc[s] = qx * bf2f(ku.x) + qy * bf2f(ku.y);
            vx[s] = bf2f(vu.x); vy[s] = bf2f(vu.y);
        } else {
            sc[s] = -1e30f; vx[s] = 0.f; vy[s] = 0.f;
        }
    }
    // butterfly-reduce valid dots across the wave
    {
        float x = sc[0];
        #pragma unroll
        for (int o = 32; o > 0; o >>= 1) x += __shfl_xor(x, o);
        sc[0] = x * SCALE;
    }
    #pragma unroll
    for (int s = 1; s < 9; ++s) {
        if (mm[s - 1]) {
            float x = sc[s];
            #pragma unroll
            for (int o = 32; o > 0; o >>= 1) x += __shfl_xor(x, o);
            sc[s] = x * SCALE;
        }
    }
    float m = sc[0];
    #pragma unroll
    for (int s = 1; s < 9; ++s) if (sc[s] > m) m = sc[s];
    float w[9], wsum = 0.f;
    #pragma unroll
    for (int s = 0; s < 9; ++s) {         // exp(-1e30-m) underflows to 0
        w[s] = __expf(sc[s] - m);
        wsum += w[s];
    }
    float inv = 1.f / wsum;
    float cx = 0.f, cy = 0.f;
    #pragma unroll
    for (int s = 0; s < 9; ++s) { cx += w[s] * vx[s]; cy += w[s] * vy[s]; }
    ushort2 o; o.x = f2bf(cx * inv); o.y = f2bf(cy * inv);
    *(ushort2*)&CTX[(size_t)node * 256 + dir * 128 + lane * 2] = o;
}

// ---------------- launch ----------------------------------------------
extern "C" void kernel_launch(void* const* d_in, const int* in_sizes, int n_in,
                              void* d_out, int out_size, void* d_ws, size_t ws_size,
                              hipStream_t stream) {
    const float* X        = (const float*)d_in[0];
    const int*   in_idx   = (const int*)d_in[1];
    const int*   out_idx  = (const int*)d_in[2];
    const int*   in_mask  = (const int*)d_in[3];
    const int*   out_mask = (const int*)d_in[4];
    const float* Wq_in  = (const float*)d_in[5];
    const float* Wk_in  = (const float*)d_in[6];
    const float* Wv_in  = (const float*)d_in[7];
    const float* ipw_in = (const float*)d_in[8];
    const float* ipb_in = (const float*)d_in[9];
    const float* ow_in  = (const float*)d_in[10];
    const float* ob_in  = (const float*)d_in[11];
    const float* Wq_out  = (const float*)d_in[12];
    const float* Wk_out  = (const float*)d_in[13];
    const float* Wv_out  = (const float*)d_in[14];
    const float* ipw_out = (const float*)d_in[15];
    const float* ipb_out = (const float*)d_in[16];
    const float* ow_out  = (const float*)d_in[17];
    const float* ob_out  = (const float*)d_in[18];
    const float* lin_w   = (const float*)d_in[19];
    const float* lin_b   = (const float*)d_in[20];

    u16* wsu    = (u16*)d_ws;
    u16* Xb     = wsu;                       // 32768*128      = 4,194,304
    u16* QKVb   = Xb + (size_t)4194304;      // 32768*768      = 25,165,824
    u16* CTXb   = QKVb + (size_t)25165824;   // 32768*256      = 8,388,608
    u16* McatbT = CTXb + (size_t)8388608;    // 768*128        = 98,304
    u16* PcatbT = McatbT + 98304;            // 128*256        = 32,768
    float* bcat = (float*)(PcatbT + 32768);  // 768 f32 (16B-aligned)
    float* bh   = bcat + 768;                // 128 f32

    xconv<<<2048, 256, 0, stream>>>(X, Xb);

    fuse_weights<<<516, 256, 0, stream>>>(
        Wq_in, Wk_in, Wv_in, ipw_in, ipb_in, ow_in, ob_in,
        Wq_out, Wk_out, Wv_out, ipw_out, ipb_out, ow_out, ob_out,
        lin_w, lin_b, McatbT, bcat, PcatbT, bh);

    gemm_qkv<3><<<dim3(256, 2), 256, 0, stream>>>(Xb, McatbT, bcat, QKVb);

    attn_kernel<<<16384, 256, 0, stream>>>(
        QKVb, in_idx, out_idx, in_mask, out_mask, CTXb);

    gemm_mfma<256, true><<<dim3(256, 1), 256, 0, stream>>>(
        CTXb, PcatbT, bh, (float*)d_out, 128);
}

// Round 4
// 77.557 us; speedup vs baseline: 1.2305x; 1.2305x over previous
//
#include <hip/hip_runtime.h>
#include <math.h>

#define NNODE 32768   // B*N
#define EE 128
constexpr float SCALE = 0.08838834764831845f; // 1/sqrt(128)

typedef unsigned short u16;
typedef __bf16 bf16x8 __attribute__((ext_vector_type(8)));
typedef float f32x4 __attribute__((ext_vector_type(4)));

__device__ __forceinline__ u16 f2bf(float f) {
    unsigned u = __float_as_uint(f);
    u += 0x7fff + ((u >> 16) & 1);       // RNE
    return (u16)(u >> 16);
}
__device__ __forceinline__ unsigned pack2bf(float lo, float hi) {
    return (unsigned)f2bf(lo) | ((unsigned)f2bf(hi) << 16);
}
// unpack uint4 (8 bf16) -> 8 f32: lo = u<<16, hi = u&0xffff0000
__device__ __forceinline__ void unpack8(uint4 u, float* f) {
    f[0] = __uint_as_float(u.x << 16);  f[1] = __uint_as_float(u.x & 0xffff0000u);
    f[2] = __uint_as_float(u.y << 16);  f[3] = __uint_as_float(u.y & 0xffff0000u);
    f[4] = __uint_as_float(u.z << 16);  f[5] = __uint_as_float(u.z & 0xffff0000u);
    f[6] = __uint_as_float(u.w << 16);  f[7] = __uint_as_float(u.w & 0xffff0000u);
}

// async global->LDS, 16B per lane; LDS dest must be wave-uniform base
__device__ __forceinline__ void gl_lds16(const void* g, void* l) {
    __builtin_amdgcn_global_load_lds(
        (const __attribute__((address_space(1))) unsigned int*)(uintptr_t)g,
        (__attribute__((address_space(3))) unsigned int*)(unsigned int)(uintptr_t)l,
        16, 0, 0);
}

// ---------------- kernel 1: fold weights -------------------------------
// McatbT[col][e]  (bf16, [768][128])  col = dir*384 + which*128 + f
// bcat[col] f32 ; PcatbT[f][e2] (bf16, [128][256]) e2 = dir*128+e ; bh f32
__global__ __launch_bounds__(256) void fuse_weights(
    const float* __restrict__ Wq_in, const float* __restrict__ Wk_in,
    const float* __restrict__ Wv_in, const float* __restrict__ ipw_in,
    const float* __restrict__ ipb_in, const float* __restrict__ ow_in,
    const float* __restrict__ ob_in,
    const float* __restrict__ Wq_out, const float* __restrict__ Wk_out,
    const float* __restrict__ Wv_out, const float* __restrict__ ipw_out,
    const float* __restrict__ ipb_out, const float* __restrict__ ow_out,
    const float* __restrict__ ob_out,
    const float* __restrict__ lin_w, const float* __restrict__ lin_b,
    u16* __restrict__ McatbT, float* __restrict__ bcat,
    u16* __restrict__ PcatbT, float* __restrict__ bh)
{
    int t = blockIdx.x * 256 + threadIdx.x;
    if (t < 98304) {
        int col = t % 768, e = t / 768;
        int dir = col / 384, rem = col % 384;
        int which = rem / 128, f = rem % 128;
        const float* W = (dir == 0)
            ? (which == 0 ? Wq_in : which == 1 ? Wk_in : Wv_in)
            : (which == 0 ? Wq_out : which == 1 ? Wk_out : Wv_out);
        const float* ipw = (dir == 0) ? ipw_in : ipw_out;
        const float* wrow = ipw + (which * EE + f) * EE;
        const float* Wrow = W + e * EE;
        float s = 0.f;
        for (int c = 0; c < EE; ++c) s += Wrow[c] * wrow[c];
        McatbT[(size_t)col * 128 + e] = f2bf(s);
    } else if (t < 98304 + 768) {
        int col = t - 98304;
        int dir = col / 384, rem = col % 384;
        int which = rem / 128, f = rem % 128;
        const float* ipb = (dir == 0) ? ipb_in : ipb_out;
        bcat[col] = ipb[which * EE + f];
    } else if (t < 98304 + 768 + 32768) {
        int u = t - (98304 + 768);
        int e2 = u / 128, f = u % 128;
        int dir = e2 / 128, e = e2 % 128;
        const float* ow = (dir == 0) ? ow_in : ow_out;
        float s = 0.f;
        for (int c = 0; c < EE; ++c)
            s += lin_w[f * 256 + dir * 128 + c] * ow[c * EE + e];
        PcatbT[(size_t)f * 256 + e2] = f2bf(s);
    } else if (t < 98304 + 768 + 32768 + 128) {
        int f = t - (98304 + 768 + 32768);
        float s = lin_b[f];
        for (int c = 0; c < EE; ++c)
            s += ob_in[c] * lin_w[f * 256 + c] + ob_out[c] * lin_w[f * 256 + 128 + c];
        bh[f] = s;
    }
}

// ---------------- kernel 2: QKV GEMM, fused f32->bf16 A-staging --------
// C[32768][768] = bf16(X)[32768][128] * McatbT[768][128]^T + bias
template<int NT>
__global__ __launch_bounds__(256) void gemm_qkv(
    const float* __restrict__ X,
    const u16* __restrict__ BT,
    const float* __restrict__ bias,
    u16* __restrict__ C)
{
    __shared__ __align__(16) u16 As[128 * 128];
    __shared__ __align__(16) u16 Bs[128 * 128];
    const int tid  = threadIdx.x;
    const int lane = tid & 63;
    const int wid  = tid >> 6;
    const int bm  = blockIdx.x * 128;
    const int bn0 = blockIdx.y * (NT * 128);
    const int wr = wid >> 1, wc = wid & 1;
    const int l15 = lane & 15, l4 = lane >> 4;

    // stage A: read f32 X, convert to bf16, swizzled ds_write (reg-staged)
    #pragma unroll
    for (int i = 0; i < 8; ++i) {
        int c = i * 256 + tid;          // chunk id 0..2047
        int r = c >> 4, cb = c & 15;
        const float* src = &X[(size_t)(bm + r) * 128 + cb * 8];
        float4 f0 = *(const float4*)src;
        float4 f1 = *(const float4*)(src + 4);
        uint4 pk;
        pk.x = pack2bf(f0.x, f0.y); pk.y = pack2bf(f0.z, f0.w);
        pk.z = pack2bf(f1.x, f1.y); pk.w = pack2bf(f1.z, f1.w);
        *(uint4*)&As[r * 128 + ((cb ^ (r & 7)) * 8)] = pk;
    }
    __syncthreads();
    bf16x8 a[4][4];
    #pragma unroll
    for (int ks = 0; ks < 4; ++ks)
        #pragma unroll
        for (int mr = 0; mr < 4; ++mr) {
            int r = wr * 64 + mr * 16 + l15;
            int kb = ks * 4 + l4;
            a[ks][mr] = *(const bf16x8*)((const char*)As + r * 256 + ((kb ^ (r & 7)) << 4));
        }

    #pragma unroll
    for (int nt = 0; nt < NT; ++nt) {
        int bn = bn0 + nt * 128;
        __syncthreads();                 // prior Bs consumers done
        #pragma unroll
        for (int i = 0; i < 8; ++i) {
            int c = i * 256 + tid;
            int r = c >> 4, cb = c & 15;
            gl_lds16(&BT[(size_t)(bn + r) * 128 + 8 * (cb ^ (r & 7))],
                     &Bs[(size_t)(c - lane) * 8]);
        }
        __syncthreads();

        f32x4 acc[4][4] = {};
        #pragma unroll
        for (int ks = 0; ks < 4; ++ks) {
            bf16x8 bfr[4];
            #pragma unroll
            for (int nc = 0; nc < 4; ++nc) {
                int r = wc * 64 + nc * 16 + l15;
                int kb = ks * 4 + l4;
                bfr[nc] = *(const bf16x8*)((const char*)Bs + r * 256 + ((kb ^ (r & 7)) << 4));
            }
            #pragma unroll
            for (int mr = 0; mr < 4; ++mr)
                #pragma unroll
                for (int nc = 0; nc < 4; ++nc)
                    acc[mr][nc] = __builtin_amdgcn_mfma_f32_16x16x32_bf16(
                        a[ks][mr], bfr[nc], acc[mr][nc], 0, 0, 0);
        }
        #pragma unroll
        for (int nc = 0; nc < 4; ++nc) {
            int col = bn + wc * 64 + nc * 16 + l15;
            float bv = bias[col];
            #pragma unroll
            for (int mr = 0; mr < 4; ++mr)
                #pragma unroll
                for (int j = 0; j < 4; ++j) {
                    int row = bm + wr * 64 + mr * 16 + l4 * 4 + j;
                    C[(size_t)row * 768 + col] = f2bf(acc[mr][nc][j] + bv);
                }
        }
    }
}

// ---------------- kernel 4: CTX GEMM + ELU (K=256) ---------------------
template<int KTOT, bool ELU_F32>
__global__ __launch_bounds__(256) void gemm_mfma(
    const u16* __restrict__ A,
    const u16* __restrict__ BT,
    const float* __restrict__ bias,
    void* __restrict__ Cout, int ldc)
{
    __shared__ __align__(16) u16 As[128 * 128];
    __shared__ __align__(16) u16 Bs[128 * 128];
    const int tid  = threadIdx.x;
    const int lane = tid & 63;
    const int wid  = tid >> 6;
    const int bm = blockIdx.x * 128;
    const int bn = blockIdx.y * 128;
    const int wr = wid >> 1, wc = wid & 1;
    const int l15 = lane & 15, l4 = lane >> 4;

    f32x4 acc[4][4] = {};

    for (int k0 = 0; k0 < KTOT; k0 += 128) {
        #pragma unroll
        for (int i = 0; i < 8; ++i) {
            int c = i * 256 + tid;
            int r = c >> 4, cb = c & 15;
            int col = k0 + 8 * (cb ^ (r & 7));
            gl_lds16(&A[(size_t)(bm + r) * KTOT + col], &As[(size_t)(c - lane) * 8]);
            gl_lds16(&BT[(size_t)(bn + r) * KTOT + col], &Bs[(size_t)(c - lane) * 8]);
        }
        __syncthreads();
        #pragma unroll
        for (int ks = 0; ks < 4; ++ks) {
            bf16x8 a[4], b[4];
            #pragma unroll
            for (int mr = 0; mr < 4; ++mr) {
                int r = wr * 64 + mr * 16 + l15;
                int kb = ks * 4 + l4;
                a[mr] = *(const bf16x8*)((const char*)As + r * 256 + ((kb ^ (r & 7)) << 4));
            }
            #pragma unroll
            for (int nc = 0; nc < 4; ++nc) {
                int r = wc * 64 + nc * 16 + l15;
                int kb = ks * 4 + l4;
                b[nc] = *(const bf16x8*)((const char*)Bs + r * 256 + ((kb ^ (r & 7)) << 4));
            }
            #pragma unroll
            for (int mr = 0; mr < 4; ++mr)
                #pragma unroll
                for (int nc = 0; nc < 4; ++nc)
                    acc[mr][nc] = __builtin_amdgcn_mfma_f32_16x16x32_bf16(
                        a[mr], b[nc], acc[mr][nc], 0, 0, 0);
        }
        __syncthreads();
    }

    #pragma unroll
    for (int nc = 0; nc < 4; ++nc) {
        int col = bn + wc * 64 + nc * 16 + l15;
        float bv = bias[col];
        #pragma unroll
        for (int mr = 0; mr < 4; ++mr) {
            #pragma unroll
            for (int j = 0; j < 4; ++j) {
                int row = bm + wr * 64 + mr * 16 + l4 * 4 + j;
                float v = acc[mr][nc][j] + bv;
                if (ELU_F32) {
                    v = v > 0.f ? v : (__expf(v) - 1.f);
                    ((float*)Cout)[(size_t)row * ldc + col] = v;
                } else {
                    ((u16*)Cout)[(size_t)row * ldc + col] = f2bf(v);
                }
            }
        }
    }
}

// ---------------- kernel 3: attention, 16 lanes per (node,dir) ---------
// 4 items/wave, 16 items/block. 8 bf16 (16B) per lane; 4-step butterfly
// within 16-lane group. K-pass then V-pass so invalid slots skip all work.
// blk&7 = (dir,batch) pair -> round-robin XCD dispatch keeps each XCD's
// gathers inside its own 4MB K/V pool.
__global__ __launch_bounds__(256) void attn_kernel(
    const u16* __restrict__ QKV,
    const int* __restrict__ in_idx, const int* __restrict__ out_idx,
    const int* __restrict__ in_mask, const int* __restrict__ out_mask,
    u16* __restrict__ CTX)
{
    const int tid = threadIdx.x;
    const int g   = tid >> 4;        // item 0..15 within block
    const int l   = tid & 15;        // lane within group
    const int pair = blockIdx.x & 7;
    const int dir = pair & 1, b = pair >> 1;
    const int nl = ((blockIdx.x >> 3) << 4) + g;       // 0..8191
    const int node = (b << 13) + nl;
    const int qoff = dir * 384;
    const int* idx = dir == 0 ? in_idx : out_idx;
    const int* msk = dir == 0 ? in_mask : out_mask;

    // neighbor ids + masks (broadcast within the 16-lane group)
    const int4 i0 = *(const int4*)&idx[(size_t)node * 8];
    const int4 i1 = *(const int4*)&idx[(size_t)node * 8 + 4];
    const int4 m0 = *(const int4*)&msk[(size_t)node * 8];
    const int4 m1 = *(const int4*)&msk[(size_t)node * 8 + 4];
    const int ii[8] = { i0.x, i0.y, i0.z, i0.w, i1.x, i1.y, i1.z, i1.w };
    const int mm[8] = { m0.x, m0.y, m0.z, m0.w, m1.x, m1.y, m1.z, m1.w };

    const u16* qrow = QKV + (size_t)node * 768 + qoff;
    float qf[8];
    unpack8(*(const uint4*)&qrow[l * 8], qf);

    // ---- K pass: scores ----
    float sc[9];
    {
        float kf[8];
        unpack8(*(const uint4*)&qrow[128 + l * 8], kf);
        float d = 0.f;
        #pragma unroll
        for (int j = 0; j < 8; ++j) d = fmaf(qf[j], kf[j], d);
        sc[0] = d;
    }
    #pragma unroll
    for (int s = 1; s < 9; ++s) {
        if (mm[s - 1]) {   // group-uniform predicate
            const u16* krow = QKV + (size_t)((b << 13) + ii[s - 1]) * 768 + qoff + 128;
            float kf[8];
            unpack8(*(const uint4*)&krow[l * 8], kf);
            float d = 0.f;
            #pragma unroll
            for (int j = 0; j < 8; ++j) d = fmaf(qf[j], kf[j], d);
            sc[s] = d;
        } else {
            sc[s] = -1e30f;
        }
    }
    // 4-step butterfly within each 16-lane group (valid slots only)
    #pragma unroll
    for (int s = 0; s < 9; ++s) {
        if (s == 0 || mm[s - 1]) {
            float x = sc[s];
            x += __shfl_xor(x, 1);
            x += __shfl_xor(x, 2);
            x += __shfl_xor(x, 4);
            x += __shfl_xor(x, 8);
            sc[s] = x * SCALE;
        }
    }
    // softmax over 9 slots (redundant across the 16 lanes)
    float m = sc[0];
    #pragma unroll
    for (int s = 1; s < 9; ++s) if (sc[s] > m) m = sc[s];
    float w[9], wsum = 0.f;
    #pragma unroll
    for (int s = 0; s < 9; ++s) { w[s] = __expf(sc[s] - m); wsum += w[s]; }
    const float inv = 1.f / wsum;

    // ---- V pass: weighted sum (valid slots only) ----
    float acc[8];
    {
        float vf[8];
        unpack8(*(const uint4*)&qrow[256 + l * 8], vf);
        #pragma unroll
        for (int j = 0; j < 8; ++j) acc[j] = w[0] * vf[j];
    }
    #pragma unroll
    for (int s = 1; s < 9; ++s) {
        if (mm[s - 1]) {
            const u16* vrow = QKV + (size_t)((b << 13) + ii[s - 1]) * 768 + qoff + 256;
            float vf[8];
            unpack8(*(const uint4*)&vrow[l * 8], vf);
            #pragma unroll
            for (int j = 0; j < 8; ++j) acc[j] = fmaf(w[s], vf[j], acc[j]);
        }
    }
    uint4 o;
    o.x = pack2bf(acc[0] * inv, acc[1] * inv);
    o.y = pack2bf(acc[2] * inv, acc[3] * inv);
    o.z = pack2bf(acc[4] * inv, acc[5] * inv);
    o.w = pack2bf(acc[6] * inv, acc[7] * inv);
    *(uint4*)&CTX[(size_t)node * 256 + dir * 128 + l * 8] = o;
}

// ---------------- launch ----------------------------------------------
extern "C" void kernel_launch(void* const* d_in, const int* in_sizes, int n_in,
                              void* d_out, int out_size, void* d_ws, size_t ws_size,
                              hipStream_t stream) {
    const float* X        = (const float*)d_in[0];
    const int*   in_idx   = (const int*)d_in[1];
    const int*   out_idx  = (const int*)d_in[2];
    const int*   in_mask  = (const int*)d_in[3];
    const int*   out_mask = (const int*)d_in[4];
    const float* Wq_in  = (const float*)d_in[5];
    const float* Wk_in  = (const float*)d_in[6];
    const float* Wv_in  = (const float*)d_in[7];
    const float* ipw_in = (const float*)d_in[8];
    const float* ipb_in = (const float*)d_in[9];
    const float* ow_in  = (const float*)d_in[10];
    const float* ob_in  = (const float*)d_in[11];
    const float* Wq_out  = (const float*)d_in[12];
    const float* Wk_out  = (const float*)d_in[13];
    const float* Wv_out  = (const float*)d_in[14];
    const float* ipw_out = (const float*)d_in[15];
    const float* ipb_out = (const float*)d_in[16];
    const float* ow_out  = (const float*)d_in[17];
    const float* ob_out  = (const float*)d_in[18];
    const float* lin_w   = (const float*)d_in[19];
    const float* lin_b   = (const float*)d_in[20];

    u16* wsu    = (u16*)d_ws;
    u16* QKVb   = wsu;                       // 32768*768      = 25,165,824
    u16* CTXb   = QKVb + (size_t)25165824;   // 32768*256      = 8,388,608
    u16* McatbT = CTXb + (size_t)8388608;    // 768*128        = 98,304
    u16* PcatbT = McatbT + 98304;            // 128*256        = 32,768
    float* bcat = (float*)(PcatbT + 32768);  // 768 f32 (16B-aligned)
    float* bh   = bcat + 768;                // 128 f32

    fuse_weights<<<516, 256, 0, stream>>>(
        Wq_in, Wk_in, Wv_in, ipw_in, ipb_in, ow_in, ob_in,
        Wq_out, Wk_out, Wv_out, ipw_out, ipb_out, ow_out, ob_out,
        lin_w, lin_b, McatbT, bcat, PcatbT, bh);

    gemm_qkv<3><<<dim3(256, 2), 256, 0, stream>>>(X, McatbT, bcat, QKVb);

    attn_kernel<<<4096, 256, 0, stream>>>(
        QKVb, in_idx, out_idx, in_mask, out_mask, CTXb);

    gemm_mfma<256, true><<<dim3(256, 1), 256, 0, stream>>>(
        CTXb, PcatbT, bh, (float*)d_out, 128);
}

// Round 5
// 72.138 us; speedup vs baseline: 1.3229x; 1.0751x over previous
//
#include <hip/hip_runtime.h>
#include <math.h>

#define NNODE 32768   // B*N
#define EE 128
constexpr float SCALE = 0.08838834764831845f; // 1/sqrt(128)

typedef unsigned short u16;
typedef __bf16 bf16x8 __attribute__((ext_vector_type(8)));
typedef float f32x4 __attribute__((ext_vector_type(4)));

__device__ __forceinline__ u16 f2bf(float f) {
    unsigned u = __float_as_uint(f);
    u += 0x7fff + ((u >> 16) & 1);       // RNE
    return (u16)(u >> 16);
}
__device__ __forceinline__ unsigned pack2bf(float lo, float hi) {
    return (unsigned)f2bf(lo) | ((unsigned)f2bf(hi) << 16);
}
// unpack uint4 (8 bf16) -> 8 f32: lo = u<<16, hi = u&0xffff0000
__device__ __forceinline__ void unpack8(uint4 u, float* f) {
    f[0] = __uint_as_float(u.x << 16);  f[1] = __uint_as_float(u.x & 0xffff0000u);
    f[2] = __uint_as_float(u.y << 16);  f[3] = __uint_as_float(u.y & 0xffff0000u);
    f[4] = __uint_as_float(u.z << 16);  f[5] = __uint_as_float(u.z & 0xffff0000u);
    f[6] = __uint_as_float(u.w << 16);  f[7] = __uint_as_float(u.w & 0xffff0000u);
}

// async global->LDS, 16B per lane; LDS dest must be wave-uniform base
__device__ __forceinline__ void gl_lds16(const void* g, void* l) {
    __builtin_amdgcn_global_load_lds(
        (const __attribute__((address_space(1))) unsigned int*)(uintptr_t)g,
        (__attribute__((address_space(3))) unsigned int*)(unsigned int)(uintptr_t)l,
        16, 0, 0);
}

// ---------------- kernel 1: fold weights -------------------------------
// McatbT[col][e]  (bf16, [768][128])  col = dir*384 + which*128 + f
// bcat[col] f32 ; PcatbT[f][e2] (bf16, [128][256]) e2 = dir*128+e ; bh f32
__global__ __launch_bounds__(256) void fuse_weights(
    const float* __restrict__ Wq_in, const float* __restrict__ Wk_in,
    const float* __restrict__ Wv_in, const float* __restrict__ ipw_in,
    const float* __restrict__ ipb_in, const float* __restrict__ ow_in,
    const float* __restrict__ ob_in,
    const float* __restrict__ Wq_out, const float* __restrict__ Wk_out,
    const float* __restrict__ Wv_out, const float* __restrict__ ipw_out,
    const float* __restrict__ ipb_out, const float* __restrict__ ow_out,
    const float* __restrict__ ob_out,
    const float* __restrict__ lin_w, const float* __restrict__ lin_b,
    u16* __restrict__ McatbT, float* __restrict__ bcat,
    u16* __restrict__ PcatbT, float* __restrict__ bh)
{
    int t = blockIdx.x * 256 + threadIdx.x;
    if (t < 98304) {
        int col = t % 768, e = t / 768;
        int dir = col / 384, rem = col % 384;
        int which = rem / 128, f = rem % 128;
        const float* W = (dir == 0)
            ? (which == 0 ? Wq_in : which == 1 ? Wk_in : Wv_in)
            : (which == 0 ? Wq_out : which == 1 ? Wk_out : Wv_out);
        const float* ipw = (dir == 0) ? ipw_in : ipw_out;
        const float* wrow = ipw + (which * EE + f) * EE;
        const float* Wrow = W + e * EE;
        float s = 0.f;
        #pragma unroll
        for (int c = 0; c < EE; c += 4) {
            float4 x = *(const float4*)&Wrow[c];
            float4 y = *(const float4*)&wrow[c];
            s = fmaf(x.x, y.x, s); s = fmaf(x.y, y.y, s);
            s = fmaf(x.z, y.z, s); s = fmaf(x.w, y.w, s);
        }
        McatbT[(size_t)col * 128 + e] = f2bf(s);
    } else if (t < 98304 + 768) {
        int col = t - 98304;
        int dir = col / 384, rem = col % 384;
        int which = rem / 128, f = rem % 128;
        const float* ipb = (dir == 0) ? ipb_in : ipb_out;
        bcat[col] = ipb[which * EE + f];
    } else if (t < 98304 + 768 + 32768) {
        int u = t - (98304 + 768);
        int e2 = u / 128, f = u % 128;
        int dir = e2 / 128, e = e2 % 128;
        const float* ow = (dir == 0) ? ow_in : ow_out;
        float s = 0.f;
        for (int c = 0; c < EE; ++c)
            s += lin_w[f * 256 + dir * 128 + c] * ow[c * EE + e];
        PcatbT[(size_t)f * 256 + e2] = f2bf(s);
    } else if (t < 98304 + 768 + 32768 + 128) {
        int f = t - (98304 + 768 + 32768);
        float s = lin_b[f];
        for (int c = 0; c < EE; ++c)
            s += ob_in[c] * lin_w[f * 256 + c] + ob_out[c] * lin_w[f * 256 + 128 + c];
        bh[f] = s;
    }
}

// ---------------- kernel 2: QKV GEMM, fused f32->bf16 A-staging --------
// C[32768][768] = bf16(X)[32768][128] * McatbT[768][128]^T + bias
template<int NT>
__global__ __launch_bounds__(256) void gemm_qkv(
    const float* __restrict__ X,
    const u16* __restrict__ BT,
    const float* __restrict__ bias,
    u16* __restrict__ C)
{
    __shared__ __align__(16) u16 As[128 * 128];
    __shared__ __align__(16) u16 Bs[128 * 128];
    const int tid  = threadIdx.x;
    const int lane = tid & 63;
    const int wid  = tid >> 6;
    const int bm  = blockIdx.x * 128;
    const int bn0 = blockIdx.y * (NT * 128);
    const int wr = wid >> 1, wc = wid & 1;
    const int l15 = lane & 15, l4 = lane >> 4;

    // stage A: read f32 X, convert to bf16, swizzled ds_write (reg-staged)
    #pragma unroll
    for (int i = 0; i < 8; ++i) {
        int c = i * 256 + tid;          // chunk id 0..2047
        int r = c >> 4, cb = c & 15;
        const float* src = &X[(size_t)(bm + r) * 128 + cb * 8];
        float4 f0 = *(const float4*)src;
        float4 f1 = *(const float4*)(src + 4);
        uint4 pk;
        pk.x = pack2bf(f0.x, f0.y); pk.y = pack2bf(f0.z, f0.w);
        pk.z = pack2bf(f1.x, f1.y); pk.w = pack2bf(f1.z, f1.w);
        *(uint4*)&As[r * 128 + ((cb ^ (r & 7)) * 8)] = pk;
    }
    __syncthreads();
    bf16x8 a[4][4];
    #pragma unroll
    for (int ks = 0; ks < 4; ++ks)
        #pragma unroll
        for (int mr = 0; mr < 4; ++mr) {
            int r = wr * 64 + mr * 16 + l15;
            int kb = ks * 4 + l4;
            a[ks][mr] = *(const bf16x8*)((const char*)As + r * 256 + ((kb ^ (r & 7)) << 4));
        }

    #pragma unroll
    for (int nt = 0; nt < NT; ++nt) {
        int bn = bn0 + nt * 128;
        __syncthreads();                 // prior Bs consumers done
        #pragma unroll
        for (int i = 0; i < 8; ++i) {
            int c = i * 256 + tid;
            int r = c >> 4, cb = c & 15;
            gl_lds16(&BT[(size_t)(bn + r) * 128 + 8 * (cb ^ (r & 7))],
                     &Bs[(size_t)(c - lane) * 8]);
        }
        __syncthreads();

        f32x4 acc[4][4] = {};
        #pragma unroll
        for (int ks = 0; ks < 4; ++ks) {
            bf16x8 bfr[4];
            #pragma unroll
            for (int nc = 0; nc < 4; ++nc) {
                int r = wc * 64 + nc * 16 + l15;
                int kb = ks * 4 + l4;
                bfr[nc] = *(const bf16x8*)((const char*)Bs + r * 256 + ((kb ^ (r & 7)) << 4));
            }
            #pragma unroll
            for (int mr = 0; mr < 4; ++mr)
                #pragma unroll
                for (int nc = 0; nc < 4; ++nc)
                    acc[mr][nc] = __builtin_amdgcn_mfma_f32_16x16x32_bf16(
                        a[ks][mr], bfr[nc], acc[mr][nc], 0, 0, 0);
        }
        #pragma unroll
        for (int nc = 0; nc < 4; ++nc) {
            int col = bn + wc * 64 + nc * 16 + l15;
            float bv = bias[col];
            #pragma unroll
            for (int mr = 0; mr < 4; ++mr)
                #pragma unroll
                for (int j = 0; j < 4; ++j) {
                    int row = bm + wr * 64 + mr * 16 + l4 * 4 + j;
                    C[(size_t)row * 768 + col] = f2bf(acc[mr][nc][j] + bv);
                }
        }
    }
}

// ---------------- kernel 4: CTX GEMM + ELU (K=256) ---------------------
template<int KTOT, bool ELU_F32>
__global__ __launch_bounds__(256) void gemm_mfma(
    const u16* __restrict__ A,
    const u16* __restrict__ BT,
    const float* __restrict__ bias,
    void* __restrict__ Cout, int ldc)
{
    __shared__ __align__(16) u16 As[128 * 128];
    __shared__ __align__(16) u16 Bs[128 * 128];
    const int tid  = threadIdx.x;
    const int lane = tid & 63;
    const int wid  = tid >> 6;
    const int bm = blockIdx.x * 128;
    const int bn = blockIdx.y * 128;
    const int wr = wid >> 1, wc = wid & 1;
    const int l15 = lane & 15, l4 = lane >> 4;

    f32x4 acc[4][4] = {};

    for (int k0 = 0; k0 < KTOT; k0 += 128) {
        #pragma unroll
        for (int i = 0; i < 8; ++i) {
            int c = i * 256 + tid;
            int r = c >> 4, cb = c & 15;
            int col = k0 + 8 * (cb ^ (r & 7));
            gl_lds16(&A[(size_t)(bm + r) * KTOT + col], &As[(size_t)(c - lane) * 8]);
            gl_lds16(&BT[(size_t)(bn + r) * KTOT + col], &Bs[(size_t)(c - lane) * 8]);
        }
        __syncthreads();
        #pragma unroll
        for (int ks = 0; ks < 4; ++ks) {
            bf16x8 a[4], b[4];
            #pragma unroll
            for (int mr = 0; mr < 4; ++mr) {
                int r = wr * 64 + mr * 16 + l15;
                int kb = ks * 4 + l4;
                a[mr] = *(const bf16x8*)((const char*)As + r * 256 + ((kb ^ (r & 7)) << 4));
            }
            #pragma unroll
            for (int nc = 0; nc < 4; ++nc) {
                int r = wc * 64 + nc * 16 + l15;
                int kb = ks * 4 + l4;
                b[nc] = *(const bf16x8*)((const char*)Bs + r * 256 + ((kb ^ (r & 7)) << 4));
            }
            #pragma unroll
            for (int mr = 0; mr < 4; ++mr)
                #pragma unroll
                for (int nc = 0; nc < 4; ++nc)
                    acc[mr][nc] = __builtin_amdgcn_mfma_f32_16x16x32_bf16(
                        a[mr], b[nc], acc[mr][nc], 0, 0, 0);
        }
        __syncthreads();
    }

    #pragma unroll
    for (int nc = 0; nc < 4; ++nc) {
        int col = bn + wc * 64 + nc * 16 + l15;
        float bv = bias[col];
        #pragma unroll
        for (int mr = 0; mr < 4; ++mr) {
            #pragma unroll
            for (int j = 0; j < 4; ++j) {
                int row = bm + wr * 64 + mr * 16 + l4 * 4 + j;
                float v = acc[mr][nc][j] + bv;
                if (ELU_F32) {
                    v = v > 0.f ? v : (__expf(v) - 1.f);
                    ((float*)Cout)[(size_t)row * ldc + col] = v;
                } else {
                    ((u16*)Cout)[(size_t)row * ldc + col] = f2bf(v);
                }
            }
        }
    }
}

// ---------------- kernel 3: attention, branch-free full-ILP ------------
// 16 lanes per (node,dir), 16 items/block. ALL K loads issued up front
// (idx entries are valid rows regardless of mask -> safe); mask applied as
// cndmask on scores; V loads issued before the shfl/softmax phase so that
// reduction work covers their latency. Invalid slots: w==0 exactly.
__global__ __launch_bounds__(256) void attn_kernel(
    const u16* __restrict__ QKV,
    const int* __restrict__ in_idx, const int* __restrict__ out_idx,
    const int* __restrict__ in_mask, const int* __restrict__ out_mask,
    u16* __restrict__ CTX)
{
    const int tid = threadIdx.x;
    const int g   = tid >> 4;        // item 0..15 within block
    const int l   = tid & 15;        // lane within group
    const int pair = blockIdx.x & 7;
    const int dir = pair & 1, b = pair >> 1;
    const int nl = ((blockIdx.x >> 3) << 4) + g;       // 0..8191
    const int node = (b << 13) + nl;
    const int qoff = dir * 384;
    const int* idx = dir == 0 ? in_idx : out_idx;
    const int* msk = dir == 0 ? in_mask : out_mask;

    const int4 i0 = *(const int4*)&idx[(size_t)node * 8];
    const int4 i1 = *(const int4*)&idx[(size_t)node * 8 + 4];
    const int4 m0 = *(const int4*)&msk[(size_t)node * 8];
    const int4 m1 = *(const int4*)&msk[(size_t)node * 8 + 4];
    const int ii[8] = { i0.x, i0.y, i0.z, i0.w, i1.x, i1.y, i1.z, i1.w };
    const int mm[8] = { m0.x, m0.y, m0.z, m0.w, m1.x, m1.y, m1.z, m1.w };

    const u16* qrow = QKV + (size_t)node * 768 + qoff;
    const u16* nrow[8];
    #pragma unroll
    for (int s = 0; s < 8; ++s)
        nrow[s] = QKV + (size_t)((b << 13) + ii[s]) * 768 + qoff;

    // ---- issue Q + all 9 K loads (all independent, all in flight) ----
    uint4 qv = *(const uint4*)&qrow[l * 8];
    uint4 kv[9];
    kv[0] = *(const uint4*)&qrow[128 + l * 8];
    #pragma unroll
    for (int s = 0; s < 8; ++s)
        kv[s + 1] = *(const uint4*)&nrow[s][128 + l * 8];

    float qf[8];
    unpack8(qv, qf);
    float sc[9];
    #pragma unroll
    for (int s = 0; s < 9; ++s) {
        float kf[8];
        unpack8(kv[s], kf);
        float d = 0.f;
        #pragma unroll
        for (int j = 0; j < 8; ++j) d = fmaf(qf[j], kf[j], d);
        sc[s] = d;
    }

    // ---- issue all 9 V loads; latency covered by shfl/softmax below ----
    uint4 vv[9];
    vv[0] = *(const uint4*)&qrow[256 + l * 8];
    #pragma unroll
    for (int s = 0; s < 8; ++s)
        vv[s + 1] = *(const uint4*)&nrow[s][256 + l * 8];

    // 4-step butterfly within each 16-lane group; 9 independent chains
    #pragma unroll
    for (int s = 0; s < 9; ++s) {
        float x = sc[s];
        x += __shfl_xor(x, 1);
        x += __shfl_xor(x, 2);
        x += __shfl_xor(x, 4);
        x += __shfl_xor(x, 8);
        sc[s] = x * SCALE;
    }
    // branch-free mask
    #pragma unroll
    for (int s = 1; s < 9; ++s)
        sc[s] = mm[s - 1] ? sc[s] : -1e30f;

    float m = sc[0];
    #pragma unroll
    for (int s = 1; s < 9; ++s) m = fmaxf(m, sc[s]);
    float w[9], wsum = 0.f;
    #pragma unroll
    for (int s = 0; s < 9; ++s) { w[s] = __expf(sc[s] - m); wsum += w[s]; }
    const float inv = 1.f / wsum;

    // ---- V accumulate (w[s]==0 exactly for invalid slots) ----
    float acc[8] = {};
    #pragma unroll
    for (int s = 0; s < 9; ++s) {
        float vf[8];
        unpack8(vv[s], vf);
        #pragma unroll
        for (int j = 0; j < 8; ++j) acc[j] = fmaf(w[s], vf[j], acc[j]);
    }
    uint4 o;
    o.x = pack2bf(acc[0] * inv, acc[1] * inv);
    o.y = pack2bf(acc[2] * inv, acc[3] * inv);
    o.z = pack2bf(acc[4] * inv, acc[5] * inv);
    o.w = pack2bf(acc[6] * inv, acc[7] * inv);
    *(uint4*)&CTX[(size_t)node * 256 + dir * 128 + l * 8] = o;
}

// ---------------- launch ----------------------------------------------
extern "C" void kernel_launch(void* const* d_in, const int* in_sizes, int n_in,
                              void* d_out, int out_size, void* d_ws, size_t ws_size,
                              hipStream_t stream) {
    const float* X        = (const float*)d_in[0];
    const int*   in_idx   = (const int*)d_in[1];
    const int*   out_idx  = (const int*)d_in[2];
    const int*   in_mask  = (const int*)d_in[3];
    const int*   out_mask = (const int*)d_in[4];
    const float* Wq_in  = (const float*)d_in[5];
    const float* Wk_in  = (const float*)d_in[6];
    const float* Wv_in  = (const float*)d_in[7];
    const float* ipw_in = (const float*)d_in[8];
    const float* ipb_in = (const float*)d_in[9];
    const float* ow_in  = (const float*)d_in[10];
    const float* ob_in  = (const float*)d_in[11];
    const float* Wq_out  = (const float*)d_in[12];
    const float* Wk_out  = (const float*)d_in[13];
    const float* Wv_out  = (const float*)d_in[14];
    const float* ipw_out = (const float*)d_in[15];
    const float* ipb_out = (const float*)d_in[16];
    const float* ow_out  = (const float*)d_in[17];
    const float* ob_out  = (const float*)d_in[18];
    const float* lin_w   = (const float*)d_in[19];
    const float* lin_b   = (const float*)d_in[20];

    u16* wsu    = (u16*)d_ws;
    u16* QKVb   = wsu;                       // 32768*768      = 25,165,824
    u16* CTXb   = QKVb + (size_t)25165824;   // 32768*256      = 8,388,608
    u16* McatbT = CTXb + (size_t)8388608;    // 768*128        = 98,304
    u16* PcatbT = McatbT + 98304;            // 128*256        = 32,768
    float* bcat = (float*)(PcatbT + 32768);  // 768 f32 (16B-aligned)
    float* bh   = bcat + 768;                // 128 f32

    fuse_weights<<<516, 256, 0, stream>>>(
        Wq_in, Wk_in, Wv_in, ipw_in, ipb_in, ow_in, ob_in,
        Wq_out, Wk_out, Wv_out, ipw_out, ipb_out, ow_out, ob_out,
        lin_w, lin_b, McatbT, bcat, PcatbT, bh);

    gemm_qkv<6><<<dim3(256, 1), 256, 0, stream>>>(X, McatbT, bcat, QKVb);

    attn_kernel<<<4096, 256, 0, stream>>>(
        QKVb, in_idx, out_idx, in_mask, out_mask, CTXb);

    gemm_mfma<256, true><<<dim3(256, 1), 256, 0, stream>>>(
        CTXb, PcatbT, bh, (float*)d_out, 128);
}

// Round 6
// 69.060 us; speedup vs baseline: 1.3819x; 1.0446x over previous
//
#include <hip/hip_runtime.h>
#include <math.h>

#define NNODE 32768   // B*N
constexpr float SCALE = 0.08838834764831845f; // 1/sqrt(128)

typedef unsigned short u16;
typedef __bf16 bf16x8 __attribute__((ext_vector_type(8)));
typedef float f32x4 __attribute__((ext_vector_type(4)));

__device__ __forceinline__ u16 f2bf(float f) {
    unsigned u = __float_as_uint(f);
    u += 0x7fff + ((u >> 16) & 1);       // RNE
    return (u16)(u >> 16);
}
__device__ __forceinline__ unsigned pack2bf(float lo, float hi) {
    return (unsigned)f2bf(lo) | ((unsigned)f2bf(hi) << 16);
}
__device__ __forceinline__ void unpack8(uint4 u, float* f) {
    f[0] = __uint_as_float(u.x << 16);  f[1] = __uint_as_float(u.x & 0xffff0000u);
    f[2] = __uint_as_float(u.y << 16);  f[3] = __uint_as_float(u.y & 0xffff0000u);
    f[4] = __uint_as_float(u.z << 16);  f[5] = __uint_as_float(u.z & 0xffff0000u);
    f[6] = __uint_as_float(u.w << 16);  f[7] = __uint_as_float(u.w & 0xffff0000u);
}
__device__ __forceinline__ float dot128(const float* __restrict__ a,
                                        const float* __restrict__ b) {
    float s = 0.f;
    #pragma unroll
    for (int c = 0; c < 128; c += 4) {
        float4 x = *(const float4*)&a[c];
        float4 y = *(const float4*)&b[c];
        s = fmaf(x.x, y.x, s); s = fmaf(x.y, y.y, s);
        s = fmaf(x.z, y.z, s); s = fmaf(x.w, y.w, s);
    }
    return s;
}

// async global->LDS, 16B per lane; LDS dest must be wave-uniform base
__device__ __forceinline__ void gl_lds16(const void* g, void* l) {
    __builtin_amdgcn_global_load_lds(
        (const __attribute__((address_space(1))) unsigned int*)(uintptr_t)g,
        (__attribute__((address_space(3))) unsigned int*)(unsigned int)(uintptr_t)l,
        16, 0, 0);
}

// ---------------- weight prep stage 1 ----------------------------------
// A = Wq@wq^T, Bm = Wk@wk^T, Wt = Wv@wv^T (all row*row dots)
// RT[g][f] = sum_e ow[e][f] * lin_w[g][dir*128+e]
__global__ __launch_bounds__(256) void wprep1(
    const float* __restrict__ ipw_in, const float* __restrict__ ipw_out,
    const float* __restrict__ Wq_in, const float* __restrict__ Wk_in,
    const float* __restrict__ Wv_in,
    const float* __restrict__ Wq_out, const float* __restrict__ Wk_out,
    const float* __restrict__ Wv_out,
    const float* __restrict__ ow_in, const float* __restrict__ ow_out,
    const float* __restrict__ lin_w,
    float* __restrict__ Af, float* __restrict__ Bmf,
    float* __restrict__ Wtf, float* __restrict__ RTf)
{
    int t = blockIdx.x * 256 + threadIdx.x;   // 0..16383
    int i = t >> 7, j = t & 127;
    int task = blockIdx.y, dir = task & 1, kind = task >> 1;
    if (kind < 3) {
        const float* ipw = dir ? ipw_out : ipw_in;
        const float* W; const float* w; float* outp;
        if (kind == 0)      { W = dir ? Wq_out : Wq_in; w = ipw;          outp = Af;  }
        else if (kind == 1) { W = dir ? Wk_out : Wk_in; w = ipw + 16384;  outp = Bmf; }
        else                { W = dir ? Wv_out : Wv_in; w = ipw + 32768;  outp = Wtf; }
        outp[dir * 16384 + i * 128 + j] = dot128(W + i * 128, w + j * 128);
    } else {
        const float* ow = dir ? ow_out : ow_in;
        const float* lw = lin_w + i * 256 + dir * 128;
        float s = 0.f;
        #pragma unroll
        for (int e = 0; e < 128; e += 4) {
            float4 l4 = *(const float4*)&lw[e];
            s = fmaf(ow[e * 128 + j],       l4.x, s);
            s = fmaf(ow[(e + 1) * 128 + j], l4.y, s);
            s = fmaf(ow[(e + 2) * 128 + j], l4.z, s);
            s = fmaf(ow[(e + 3) * 128 + j], l4.w, s);
        }
        RTf[dir * 16384 + i * 128 + j] = s;
    }
}

// ---------------- weight prep stage 2 ----------------------------------
// Bcat[dir*128+d][c] = G_dir[c][d] = sum_f A[c][f]*Bm[d][f]   (bf16)
// QfT[g][dir*128+c]  = Qf_dir[c][g] = sum_f Wt[c][f]*RT[g][f] (bf16)
// ycat[dir*128+d] = sum_f Bm[d][f]*bq[f]
// bfin[g] = lin_b[g] + sum_dir( bv.RT_row_g + ob.linw_row_g )
__global__ __launch_bounds__(256) void wprep2(
    const float* __restrict__ Af, const float* __restrict__ Bmf,
    const float* __restrict__ Wtf, const float* __restrict__ RTf,
    const float* __restrict__ ipb_in, const float* __restrict__ ipb_out,
    const float* __restrict__ lin_w, const float* __restrict__ lin_b,
    const float* __restrict__ ob_in, const float* __restrict__ ob_out,
    u16* __restrict__ Bcat, u16* __restrict__ QfT,
    float* __restrict__ ycat, float* __restrict__ bfin)
{
    int task = blockIdx.y;
    int t = blockIdx.x * 256 + threadIdx.x;
    if (task < 2) {
        int dir = task, i = t >> 7, j = t & 127;          // i=d, j=c
        float s = dot128(Af + dir * 16384 + j * 128, Bmf + dir * 16384 + i * 128);
        Bcat[(size_t)(dir * 128 + i) * 128 + j] = f2bf(s);
    } else if (task < 4) {
        int dir = task - 2, i = t >> 7, j = t & 127;      // i=g, j=c
        float s = dot128(Wtf + dir * 16384 + j * 128, RTf + dir * 16384 + i * 128);
        QfT[(size_t)i * 256 + dir * 128 + j] = f2bf(s);
    } else {
        if (t < 256) {
            int dir = t >> 7, d = t & 127;
            const float* bq = dir ? ipb_out : ipb_in;
            const float* rb = Bmf + dir * 16384 + d * 128;
            float s = 0.f;
            for (int f = 0; f < 128; ++f) s = fmaf(rb[f], bq[f], s);
            ycat[t] = s;
        } else if (t < 384) {
            int g = t - 256;
            float s = lin_b[g];
            #pragma unroll
            for (int dir = 0; dir < 2; ++dir) {
                const float* bv = (dir ? ipb_out : ipb_in) + 256;
                const float* rt = RTf + dir * 16384 + g * 128;
                const float* ob = dir ? ob_out : ob_in;
                const float* lw = lin_w + g * 256 + dir * 128;
                for (int c = 0; c < 128; ++c)
                    s += bv[c] * rt[c] + ob[c] * lw[c];
            }
            bfin[g] = s;
        }
    }
}

// ---------------- kernel: Y GEMM (also emits Xb) -----------------------
// Y[32768][256] = bf16(X) @ Bcat^T + ycat ; Xb = bf16(X) written en route
template<int NT>
__global__ __launch_bounds__(256) void gemm_y(
    const float* __restrict__ X,
    const u16* __restrict__ BT,
    const float* __restrict__ bias,
    u16* __restrict__ C, u16* __restrict__ Xb)
{
    __shared__ __align__(16) u16 As[128 * 128];
    __shared__ __align__(16) u16 Bs[128 * 128];
    const int tid  = threadIdx.x;
    const int lane = tid & 63;
    const int wid  = tid >> 6;
    const int bm  = blockIdx.x * 128;
    const int wr = wid >> 1, wc = wid & 1;
    const int l15 = lane & 15, l4 = lane >> 4;

    // stage A: read f32 X, convert, swizzled ds_write; also write Xb global
    #pragma unroll
    for (int i = 0; i < 8; ++i) {
        int c = i * 256 + tid;          // chunk id 0..2047
        int r = c >> 4, cb = c & 15;
        const float* src = &X[(size_t)(bm + r) * 128 + cb * 8];
        float4 f0 = *(const float4*)src;
        float4 f1 = *(const float4*)(src + 4);
        uint4 pk;
        pk.x = pack2bf(f0.x, f0.y); pk.y = pack2bf(f0.z, f0.w);
        pk.z = pack2bf(f1.x, f1.y); pk.w = pack2bf(f1.z, f1.w);
        *(uint4*)&As[r * 128 + ((cb ^ (r & 7)) * 8)] = pk;
        *(uint4*)&Xb[(size_t)(bm + r) * 128 + cb * 8] = pk;
    }
    __syncthreads();
    bf16x8 a[4][4];
    #pragma unroll
    for (int ks = 0; ks < 4; ++ks)
        #pragma unroll
        for (int mr = 0; mr < 4; ++mr) {
            int r = wr * 64 + mr * 16 + l15;
            int kb = ks * 4 + l4;
            a[ks][mr] = *(const bf16x8*)((const char*)As + r * 256 + ((kb ^ (r & 7)) << 4));
        }

    #pragma unroll
    for (int nt = 0; nt < NT; ++nt) {
        int bn = nt * 128;
        __syncthreads();
        #pragma unroll
        for (int i = 0; i < 8; ++i) {
            int c = i * 256 + tid;
            int r = c >> 4, cb = c & 15;
            gl_lds16(&BT[(size_t)(bn + r) * 128 + 8 * (cb ^ (r & 7))],
                     &Bs[(size_t)(c - lane) * 8]);
        }
        __syncthreads();

        f32x4 acc[4][4] = {};
        #pragma unroll
        for (int ks = 0; ks < 4; ++ks) {
            bf16x8 bfr[4];
            #pragma unroll
            for (int nc = 0; nc < 4; ++nc) {
                int r = wc * 64 + nc * 16 + l15;
                int kb = ks * 4 + l4;
                bfr[nc] = *(const bf16x8*)((const char*)Bs + r * 256 + ((kb ^ (r & 7)) << 4));
            }
            #pragma unroll
            for (int mr = 0; mr < 4; ++mr)
                #pragma unroll
                for (int nc = 0; nc < 4; ++nc)
                    acc[mr][nc] = __builtin_amdgcn_mfma_f32_16x16x32_bf16(
                        a[ks][mr], bfr[nc], acc[mr][nc], 0, 0, 0);
        }
        #pragma unroll
        for (int nc = 0; nc < 4; ++nc) {
            int col = bn + wc * 64 + nc * 16 + l15;
            float bv = bias[col];
            #pragma unroll
            for (int mr = 0; mr < 4; ++mr)
                #pragma unroll
                for (int j = 0; j < 4; ++j) {
                    int row = bm + wr * 64 + mr * 16 + l4 * 4 + j;
                    C[(size_t)row * 256 + col] = f2bf(acc[mr][nc][j] + bv);
                }
        }
    }
}

// ---------------- output GEMM + ELU (K=256) ----------------------------
template<int KTOT, bool ELU_F32>
__global__ __launch_bounds__(256) void gemm_mfma(
    const u16* __restrict__ A,
    const u16* __restrict__ BT,
    const float* __restrict__ bias,
    void* __restrict__ Cout, int ldc)
{
    __shared__ __align__(16) u16 As[128 * 128];
    __shared__ __align__(16) u16 Bs[128 * 128];
    const int tid  = threadIdx.x;
    const int lane = tid & 63;
    const int wid  = tid >> 6;
    const int bm = blockIdx.x * 128;
    const int bn = blockIdx.y * 128;
    const int wr = wid >> 1, wc = wid & 1;
    const int l15 = lane & 15, l4 = lane >> 4;

    f32x4 acc[4][4] = {};

    for (int k0 = 0; k0 < KTOT; k0 += 128) {
        #pragma unroll
        for (int i = 0; i < 8; ++i) {
            int c = i * 256 + tid;
            int r = c >> 4, cb = c & 15;
            int col = k0 + 8 * (cb ^ (r & 7));
            gl_lds16(&A[(size_t)(bm + r) * KTOT + col], &As[(size_t)(c - lane) * 8]);
            gl_lds16(&BT[(size_t)(bn + r) * KTOT + col], &Bs[(size_t)(c - lane) * 8]);
        }
        __syncthreads();
        #pragma unroll
        for (int ks = 0; ks < 4; ++ks) {
            bf16x8 a[4], b[4];
            #pragma unroll
            for (int mr = 0; mr < 4; ++mr) {
                int r = wr * 64 + mr * 16 + l15;
                int kb = ks * 4 + l4;
                a[mr] = *(const bf16x8*)((const char*)As + r * 256 + ((kb ^ (r & 7)) << 4));
            }
            #pragma unroll
            for (int nc = 0; nc < 4; ++nc) {
                int r = wc * 64 + nc * 16 + l15;
                int kb = ks * 4 + l4;
                b[nc] = *(const bf16x8*)((const char*)Bs + r * 256 + ((kb ^ (r & 7)) << 4));
            }
            #pragma unroll
            for (int mr = 0; mr < 4; ++mr)
                #pragma unroll
                for (int nc = 0; nc < 4; ++nc)
                    acc[mr][nc] = __builtin_amdgcn_mfma_f32_16x16x32_bf16(
                        a[mr], b[nc], acc[mr][nc], 0, 0, 0);
        }
        __syncthreads();
    }

    #pragma unroll
    for (int nc = 0; nc < 4; ++nc) {
        int col = bn + wc * 64 + nc * 16 + l15;
        float bv = bias[col];
        #pragma unroll
        for (int mr = 0; mr < 4; ++mr) {
            #pragma unroll
            for (int j = 0; j < 4; ++j) {
                int row = bm + wr * 64 + mr * 16 + l4 * 4 + j;
                float v = acc[mr][nc][j] + bv;
                if (ELU_F32) {
                    v = v > 0.f ? v : (__expf(v) - 1.f);
                    ((float*)Cout)[(size_t)row * ldc + col] = v;
                } else {
                    ((u16*)Cout)[(size_t)row * ldc + col] = f2bf(v);
                }
            }
        }
    }
}

// ---------------- attention: Y.X scores, XCTX = sum w*X ----------------
// 16 lanes per (node,dir); gathers only Xb rows (shared across dirs).
// Scores s'(n,m) = Y_n . Xb_m (softmax-shift-equivalent to reference).
// XCTX = (sum_s w_s Xb_s)/sum w  -> V-projection folded into gemm_out.
__global__ __launch_bounds__(256) void attn_kernel(
    const u16* __restrict__ Y, const u16* __restrict__ Xb,
    const int* __restrict__ in_idx, const int* __restrict__ out_idx,
    const int* __restrict__ in_mask, const int* __restrict__ out_mask,
    u16* __restrict__ XCTX)
{
    const int tid = threadIdx.x;
    const int g   = tid >> 4;        // item 0..15 within block
    const int l   = tid & 15;        // lane within group
    const int pair = blockIdx.x & 7;
    const int dir = pair & 1, b = pair >> 1;
    const int nl = ((blockIdx.x >> 3) << 4) + g;       // 0..8191
    const int node = (b << 13) + nl;
    const int* idx = dir == 0 ? in_idx : out_idx;
    const int* msk = dir == 0 ? in_mask : out_mask;

    const int4 i0 = *(const int4*)&idx[(size_t)node * 8];
    const int4 i1 = *(const int4*)&idx[(size_t)node * 8 + 4];
    const int4 m0 = *(const int4*)&msk[(size_t)node * 8];
    const int4 m1 = *(const int4*)&msk[(size_t)node * 8 + 4];
    const int ii[8] = { i0.x, i0.y, i0.z, i0.w, i1.x, i1.y, i1.z, i1.w };
    const int mm[8] = { m0.x, m0.y, m0.z, m0.w, m1.x, m1.y, m1.z, m1.w };

    // issue all loads up front: Y row (self) + 9 Xb rows
    uint4 yv = *(const uint4*)&Y[(size_t)node * 256 + dir * 128 + l * 8];
    uint4 xv[9];
    xv[0] = *(const uint4*)&Xb[(size_t)node * 128 + l * 8];
    #pragma unroll
    for (int s = 0; s < 8; ++s)
        xv[s + 1] = *(const uint4*)&Xb[(size_t)((b << 13) + ii[s]) * 128 + l * 8];

    float yf[8];
    unpack8(yv, yf);
    float sc[9];
    #pragma unroll
    for (int s = 0; s < 9; ++s) {
        float kf[8];
        unpack8(xv[s], kf);
        float d = 0.f;
        #pragma unroll
        for (int j = 0; j < 8; ++j) d = fmaf(yf[j], kf[j], d);
        sc[s] = d;
    }

    // 4-step butterfly within each 16-lane group; 9 independent chains
    #pragma unroll
    for (int s = 0; s < 9; ++s) {
        float x = sc[s];
        x += __shfl_xor(x, 1);
        x += __shfl_xor(x, 2);
        x += __shfl_xor(x, 4);
        x += __shfl_xor(x, 8);
        sc[s] = x * SCALE;
    }
    #pragma unroll
    for (int s = 1; s < 9; ++s)
        sc[s] = mm[s - 1] ? sc[s] : -1e30f;

    float m = sc[0];
    #pragma unroll
    for (int s = 1; s < 9; ++s) m = fmaxf(m, sc[s]);
    float w[9], wsum = 0.f;
    #pragma unroll
    for (int s = 0; s < 9; ++s) { w[s] = __expf(sc[s] - m); wsum += w[s]; }
    const float inv = 1.f / wsum;

    // weighted sum of the SAME gathered rows (w==0 exactly for invalid)
    float acc[8] = {};
    #pragma unroll
    for (int s = 0; s < 9; ++s) {
        float vf[8];
        unpack8(xv[s], vf);
        #pragma unroll
        for (int j = 0; j < 8; ++j) acc[j] = fmaf(w[s], vf[j], acc[j]);
    }
    uint4 o;
    o.x = pack2bf(acc[0] * inv, acc[1] * inv);
    o.y = pack2bf(acc[2] * inv, acc[3] * inv);
    o.z = pack2bf(acc[4] * inv, acc[5] * inv);
    o.w = pack2bf(acc[6] * inv, acc[7] * inv);
    *(uint4*)&XCTX[(size_t)node * 256 + dir * 128 + l * 8] = o;
}

// ---------------- launch ----------------------------------------------
extern "C" void kernel_launch(void* const* d_in, const int* in_sizes, int n_in,
                              void* d_out, int out_size, void* d_ws, size_t ws_size,
                              hipStream_t stream) {
    const float* X        = (const float*)d_in[0];
    const int*   in_idx   = (const int*)d_in[1];
    const int*   out_idx  = (const int*)d_in[2];
    const int*   in_mask  = (const int*)d_in[3];
    const int*   out_mask = (const int*)d_in[4];
    const float* Wq_in  = (const float*)d_in[5];
    const float* Wk_in  = (const float*)d_in[6];
    const float* Wv_in  = (const float*)d_in[7];
    const float* ipw_in = (const float*)d_in[8];
    const float* ipb_in = (const float*)d_in[9];
    const float* ow_in  = (const float*)d_in[10];
    const float* ob_in  = (const float*)d_in[11];
    const float* Wq_out  = (const float*)d_in[12];
    const float* Wk_out  = (const float*)d_in[13];
    const float* Wv_out  = (const float*)d_in[14];
    const float* ipw_out = (const float*)d_in[15];
    const float* ipb_out = (const float*)d_in[16];
    const float* ow_out  = (const float*)d_in[17];
    const float* ob_out  = (const float*)d_in[18];
    const float* lin_w   = (const float*)d_in[19];
    const float* lin_b   = (const float*)d_in[20];

    char* wsb = (char*)d_ws;
    u16*   Xbw  = (u16*)(wsb + 0);                    //  8,388,608 B
    u16*   Yw   = (u16*)(wsb + 8388608);              // 16,777,216 B
    u16*   XCTX = (u16*)(wsb + 25165824);             // 16,777,216 B
    u16*   Bcat = (u16*)(wsb + 41943040);             //     65,536 B
    u16*   QfT  = (u16*)(wsb + 42008576);             //     65,536 B
    float* Af   = (float*)(wsb + 42074112);           //    131,072 B
    float* Bmf  = (float*)(wsb + 42205184);
    float* Wtf  = (float*)(wsb + 42336256);
    float* RTf  = (float*)(wsb + 42467328);
    float* ycat = (float*)(wsb + 42598400);           //      1,024 B
    float* bfin = (float*)(wsb + 42599424);           //        512 B

    wprep1<<<dim3(64, 8), 256, 0, stream>>>(
        ipw_in, ipw_out, Wq_in, Wk_in, Wv_in, Wq_out, Wk_out, Wv_out,
        ow_in, ow_out, lin_w, Af, Bmf, Wtf, RTf);

    wprep2<<<dim3(64, 5), 256, 0, stream>>>(
        Af, Bmf, Wtf, RTf, ipb_in, ipb_out, lin_w, lin_b, ob_in, ob_out,
        Bcat, QfT, ycat, bfin);

    gemm_y<2><<<dim3(256, 1), 256, 0, stream>>>(X, Bcat, ycat, Yw, Xbw);

    attn_kernel<<<4096, 256, 0, stream>>>(
        Yw, Xbw, in_idx, out_idx, in_mask, out_mask, XCTX);

    gemm_mfma<256, true><<<dim3(256, 1), 256, 0, stream>>>(
        XCTX, QfT, bfin, (float*)d_out, 128);
}